// Round 1
// 626.858 us; speedup vs baseline: 1.0476x; 1.0476x over previous
//
#include <hip/hip_runtime.h>

#define NN 50000      // nodes
#define NR 10         // relations (one direction)
#define R2 21         // 2*NR+1
#define NE 500000     // triples
#define NB 16384      // batch
#define HID 64
#define SCAN_B 1024
#define M_CELLS (R2 * NN)   // 1,050,000 cells (ss-major: col = ss*NN + src)

// ---- hist: celloff cell counts (dst*21+ss) w/ rank capture; batch flags ------
__global__ void hist_kernel(const int* __restrict__ triples, const int* __restrict__ batch,
                            int* __restrict__ celloff, int* __restrict__ rank,
                            int* __restrict__ flag) {
    int t = blockIdx.x * blockDim.x + threadIdx.x;
    if (t < NE) {
        int s = triples[3 * t], p = triples[3 * t + 1], o = triples[3 * t + 2];
        rank[t]      = atomicAdd(celloff + s * R2 + p, 1);           // fwd: dst=s, ss=p
        rank[t + NE] = atomicAdd(celloff + o * R2 + (p + NR), 1);    // bwd: dst=o, ss=p+NR
    } else if (t < NE + NN) {
        int v = t - NE;
        celloff[v * R2 + 2 * NR] = 1;   // self-loop cell: always exactly 1
    } else if (t < NE + NN + 2 * NB) {
        int j = t - (NE + NN);
        int node = (j < NB) ? batch[3 * j] : batch[3 * (j - NB) + 2];
        flag[node] = 1;                 // idempotent
    }
}

// ---- vals[ss*NN+x] = 1/cnt via the celloff-count permutation (pre-scan!) -----
__global__ void recip_kernel(const int* __restrict__ celloff, float* __restrict__ vals) {
    int i = blockIdx.x * blockDim.x + threadIdx.x;
    if (i >= M_CELLS) return;
    unsigned ss = (unsigned)i / NN;
    int x = i - ss * NN;
    int c;
    if (ss < NR)          c = celloff[x * R2 + ss + NR];   // #(p=ss, o=x)
    else if (ss < 2 * NR) c = celloff[x * R2 + ss - NR];   // #(p=ss-NR, s=x)
    else                  c = 1;                           // self-loop
    vals[i] = 1.0f / (float)c;        // inf for never-referenced cols (never read)
}

// ---- 2-level exclusive scan, 2 items per thread ------------------------------
__global__ void scan1_kernel(int* __restrict__ data, int* __restrict__ bsums, int M) {
    __shared__ int sm[SCAN_B];
    int i0 = (blockIdx.x * SCAN_B + threadIdx.x) * 2;
    int x0 = (i0     < M) ? data[i0]     : 0;
    int x1 = (i0 + 1 < M) ? data[i0 + 1] : 0;
    int s = x0 + x1;
    sm[threadIdx.x] = s; __syncthreads();
    for (int off = 1; off < SCAN_B; off <<= 1) {
        int v = (threadIdx.x >= off) ? sm[threadIdx.x - off] : 0;
        __syncthreads();
        sm[threadIdx.x] += v;
        __syncthreads();
    }
    int excl = sm[threadIdx.x] - s;
    if (i0     < M) data[i0]     = excl;
    if (i0 + 1 < M) data[i0 + 1] = excl + x0;
    if (threadIdx.x == SCAN_B - 1) bsums[blockIdx.x] = sm[SCAN_B - 1];
}
__global__ void scan2_kernel(int* __restrict__ bsums, int nb, int* __restrict__ total_out) {
    __shared__ int sm[SCAN_B];
    int x = (threadIdx.x < nb) ? bsums[threadIdx.x] : 0;
    sm[threadIdx.x] = x; __syncthreads();
    for (int off = 1; off < SCAN_B; off <<= 1) {
        int v = (threadIdx.x >= off) ? sm[threadIdx.x - off] : 0;
        __syncthreads();
        sm[threadIdx.x] += v;
        __syncthreads();
    }
    if (threadIdx.x < nb) bsums[threadIdx.x] = sm[threadIdx.x] - x;
    if (threadIdx.x == SCAN_B - 1) *total_out = sm[SCAN_B - 1];
}
__global__ void scan3_kernel(int* __restrict__ data, const int* __restrict__ bsums, int M) {
    int i0 = (blockIdx.x * SCAN_B + threadIdx.x) * 2;
    int b = bsums[blockIdx.x];
    if (i0     < M) data[i0]     += b;
    if (i0 + 1 < M) data[i0 + 1] += b;
}

// ---- scatter (atomic-free via rank) + mark needed cols -----------------------
// colflag[col]=1 for every col appearing in a flagged dst's edge list.
__global__ void scatter_kernel(const int* __restrict__ triples,
                               const int* __restrict__ celloff,
                               const int* __restrict__ rank,
                               const int* __restrict__ flag,
                               int* __restrict__ pay,
                               int* __restrict__ colflag) {
    int t = blockIdx.x * blockDim.x + threadIdx.x;
    if (t < NE) {
        int s = triples[3 * t], p = triples[3 * t + 1], o = triples[3 * t + 2];
        int pos1 = celloff[s * R2 + p] + rank[t];
        pay[pos1] = p * NN + o;                          // fwd: src=o
        int pos2 = celloff[o * R2 + (p + NR)] + rank[t + NE];
        pay[pos2] = (p + NR) * NN + s;                   // bwd: src=s
        if (flag[s]) colflag[p * NN + o] = 1;
        if (flag[o]) colflag[(p + NR) * NN + s] = 1;
    } else if (t < NE + NN) {
        int v = t - NE;
        int pos = celloff[v * R2 + 2 * NR];
        pay[pos] = 2 * NR * NN + v;
        if (flag[v]) colflag[2 * NR * NN + v] = 1;
    }
}

// ---- collist[coloff[c]] = c for flagged cols (coloff = scanned colflag) ------
__global__ void collist_kernel(const int* __restrict__ coloff, int* __restrict__ collist) {
    int i = blockIdx.x * blockDim.x + threadIdx.x;
    if (i >= M_CELLS) return;
    int a = coloff[i], b = coloff[i + 1];
    if (b > a) collist[a] = i;
}

// ---- layer 1: wave per dst; lane-parallel edge fetch; ILP-8 w0 row loads -----
__global__ __launch_bounds__(256) void layer1_kernel(const int* __restrict__ celloff,
                                                     const int* __restrict__ pay,
                                                     const float* __restrict__ vals,
                                                     const float* __restrict__ w0,
                                                     const float* __restrict__ b0,
                                                     float* __restrict__ h) {
    int wv = (blockIdx.x * blockDim.x + threadIdx.x) >> 6;
    int lane = threadIdx.x & 63;
    if (wv >= NN) return;
    int dst = __builtin_amdgcn_readfirstlane(wv);
    int beg = celloff[dst * R2];
    int end = celloff[(dst + 1) * R2];
    float acc = b0[lane];
    for (int base = beg; base < end; base += 64) {
        int idx = base + lane;
        int colv = (idx < end) ? pay[idx] : 2 * NR * NN;
        float vv = (idx < end) ? vals[colv] : 0.f;
        int m = __builtin_amdgcn_readfirstlane(min(64, end - base));
        int e = 0;
        for (; e + 8 <= m; e += 8) {
            int c0_ = __shfl(colv, e,     64); float v0 = __shfl(vv, e,     64);
            int c1_ = __shfl(colv, e + 1, 64); float v1 = __shfl(vv, e + 1, 64);
            int c2_ = __shfl(colv, e + 2, 64); float v2 = __shfl(vv, e + 2, 64);
            int c3_ = __shfl(colv, e + 3, 64); float v3 = __shfl(vv, e + 3, 64);
            int c4_ = __shfl(colv, e + 4, 64); float v4 = __shfl(vv, e + 4, 64);
            int c5_ = __shfl(colv, e + 5, 64); float v5 = __shfl(vv, e + 5, 64);
            int c6_ = __shfl(colv, e + 6, 64); float v6 = __shfl(vv, e + 6, 64);
            int c7_ = __shfl(colv, e + 7, 64); float v7 = __shfl(vv, e + 7, 64);
            float f0 = w0[(size_t)c0_ * HID + lane];
            float f1 = w0[(size_t)c1_ * HID + lane];
            float f2 = w0[(size_t)c2_ * HID + lane];
            float f3 = w0[(size_t)c3_ * HID + lane];
            float f4 = w0[(size_t)c4_ * HID + lane];
            float f5 = w0[(size_t)c5_ * HID + lane];
            float f6 = w0[(size_t)c6_ * HID + lane];
            float f7 = w0[(size_t)c7_ * HID + lane];
            acc += v0 * f0; acc += v1 * f1; acc += v2 * f2; acc += v3 * f3;
            acc += v4 * f4; acc += v5 * f5; acc += v6 * f6; acc += v7 * f7;
        }
        for (; e < m; ++e) {
            int   c = __shfl(colv, e, 64);
            float v = __shfl(vv, e, 64);
            acc += v * w0[(size_t)c * HID + lane];
        }
    }
    h[(size_t)dst * HID + lane] = acc;
}

// ---- gcompute: g[gi] = h[src] @ w1[ss] for each flagged col (gi = coloff[col])
// 32 cols/block; collist is ss-major so blocks are (almost always) ss-uniform:
// w1[ss] staged once in LDS, h rows staged, register-tiled 8-rows/wave matmul.
__global__ __launch_bounds__(256) void gcompute_kernel(const int* __restrict__ collist,
                                                       const int* __restrict__ ncols_p,
                                                       const float* __restrict__ h,
                                                       const float* __restrict__ w1,
                                                       float* __restrict__ g) {
    __shared__ float w1s[HID * HID];     // 16 KB
    __shared__ float hs[32 * 68];        // 32 staged h rows, pad stride 68
    const int ncols = *ncols_p;
    const int base = blockIdx.x * 32;
    if (base >= ncols) return;           // uniform early-exit
    const int lane = threadIdx.x & 63;
    const int wid  = __builtin_amdgcn_readfirstlane(threadIdx.x >> 6);
    const int trow = threadIdx.x >> 3;   // 0..31
    const int tc8  = threadIdx.x & 7;    // 0..7

    int lastr = min(base + 31, ncols - 1);
    int col0 = collist[base];
    int colL = collist[lastr];
    int ss0 = (int)((unsigned)col0 / NN);
    int ssL = (int)((unsigned)colL / NN);
    bool uni = (ss0 == ssL);

    {   // stage w1[ss0] (4096 floats = 1024 float4, 256 threads x 4)
        const float4* src = (const float4*)(w1 + (size_t)ss0 * HID * HID);
        float4* dst = (float4*)w1s;
#pragma unroll
        for (int i = 0; i < 4; ++i) dst[threadIdx.x + 256 * i] = src[threadIdx.x + 256 * i];
    }
    {   // stage h rows for this block's cols
        int myrow = base + trow;
        int mycol = (myrow < ncols) ? collist[myrow] : col0;
        int myss  = (int)((unsigned)mycol / NN);
        int mysrc = mycol - myss * NN;
#pragma unroll
        for (int it = 0; it < 2; ++it) {
            int c = tc8 + 8 * it;        // float4 index 0..15
            float4 v = *(const float4*)(h + (size_t)mysrc * HID + c * 4);
            *(float4*)(hs + trow * 68 + c * 4) = v;
        }
    }
    __syncthreads();

    float acc[8];
#pragma unroll
    for (int i = 0; i < 8; ++i) acc[i] = 0.f;

    if (uni) {
#pragma unroll
        for (int kc = 0; kc < 4; ++kc) {
            float wk[16];
#pragma unroll
            for (int k = 0; k < 16; ++k) wk[k] = w1s[(kc * 16 + k) * HID + lane];
#pragma unroll
            for (int ii = 0; ii < 8; ++ii) {
                const float* lp = hs + (wid * 8 + ii) * 68 + kc * 16;
                float4 a0 = *(const float4*)(lp);
                float4 a1 = *(const float4*)(lp + 4);
                float4 a2 = *(const float4*)(lp + 8);
                float4 a3 = *(const float4*)(lp + 12);
                float a = acc[ii];
                a += a0.x * wk[0];  a += a0.y * wk[1];  a += a0.z * wk[2];  a += a0.w * wk[3];
                a += a1.x * wk[4];  a += a1.y * wk[5];  a += a1.z * wk[6];  a += a1.w * wk[7];
                a += a2.x * wk[8];  a += a2.y * wk[9];  a += a2.z * wk[10]; a += a2.w * wk[11];
                a += a3.x * wk[12]; a += a3.y * wk[13]; a += a3.z * wk[14]; a += a3.w * wk[15];
                acc[ii] = a;
            }
        }
    } else {
        // rare ss-boundary block (~20 of ~12.7k): per-row w1 from global
        for (int ii = 0; ii < 8; ++ii) {
            int r = base + wid * 8 + ii;
            if (r >= ncols) continue;
            int c = collist[r];
            int ss = (int)((unsigned)c / NN);
            const float* wp = w1 + (size_t)ss * HID * HID;
            const float* lp = hs + (wid * 8 + ii) * 68;
            float a = 0.f;
            for (int k = 0; k < HID; ++k) a += lp[k] * wp[k * HID + lane];
            acc[ii] = a;
        }
    }

#pragma unroll
    for (int ii = 0; ii < 8; ++ii) {
        int r = base + wid * 8 + ii;
        if (r < ncols) g[(size_t)r * HID + lane] = acc[ii];
    }
}

// ---- layer 2: wave per flagged dst; ILP-8 gather of precomputed g rows -------
__global__ __launch_bounds__(256) void layer2_kernel(const int* __restrict__ celloff,
                                                     const int* __restrict__ pay,
                                                     const float* __restrict__ vals,
                                                     const int* __restrict__ coloff,
                                                     const float* __restrict__ g,
                                                     const float* __restrict__ b1,
                                                     const int* __restrict__ flag,
                                                     float* __restrict__ nodes) {
    int wv = (blockIdx.x * blockDim.x + threadIdx.x) >> 6;
    int lane = threadIdx.x & 63;
    if (wv >= NN) return;
    int dst = __builtin_amdgcn_readfirstlane(wv);
    if (!flag[dst]) return;
    int beg = celloff[dst * R2];
    int end = celloff[(dst + 1) * R2];      // includes self-loop cell (val=1)
    float acc = b1[lane];
    for (int base = beg; base < end; base += 64) {
        int idx = base + lane;
        int colv = (idx < end) ? pay[idx] : 0;
        float vv = (idx < end) ? vals[colv] : 0.f;
        int gv   = (idx < end) ? coloff[colv] : 0;
        int m = __builtin_amdgcn_readfirstlane(min(64, end - base));
        int e = 0;
        for (; e + 8 <= m; e += 8) {
            int g0 = __shfl(gv, e,     64); float v0 = __shfl(vv, e,     64);
            int g1 = __shfl(gv, e + 1, 64); float v1 = __shfl(vv, e + 1, 64);
            int g2 = __shfl(gv, e + 2, 64); float v2 = __shfl(vv, e + 2, 64);
            int g3 = __shfl(gv, e + 3, 64); float v3 = __shfl(vv, e + 3, 64);
            int g4 = __shfl(gv, e + 4, 64); float v4 = __shfl(vv, e + 4, 64);
            int g5 = __shfl(gv, e + 5, 64); float v5 = __shfl(vv, e + 5, 64);
            int g6 = __shfl(gv, e + 6, 64); float v6 = __shfl(vv, e + 6, 64);
            int g7 = __shfl(gv, e + 7, 64); float v7 = __shfl(vv, e + 7, 64);
            float f0 = g[(size_t)g0 * HID + lane];
            float f1 = g[(size_t)g1 * HID + lane];
            float f2 = g[(size_t)g2 * HID + lane];
            float f3 = g[(size_t)g3 * HID + lane];
            float f4 = g[(size_t)g4 * HID + lane];
            float f5 = g[(size_t)g5 * HID + lane];
            float f6 = g[(size_t)g6 * HID + lane];
            float f7 = g[(size_t)g7 * HID + lane];
            acc += v0 * f0; acc += v1 * f1; acc += v2 * f2; acc += v3 * f3;
            acc += v4 * f4; acc += v5 * f5; acc += v6 * f6; acc += v7 * f7;
        }
        for (; e < m; ++e) {
            int   gi = __shfl(gv, e, 64);
            float v  = __shfl(vv, e, 64);
            acc += v * g[(size_t)gi * HID + lane];
        }
    }
    nodes[(size_t)dst * HID + lane] = acc;
}

// ---- scores: wave per batch item (nodes indexed directly) --------------------
__global__ __launch_bounds__(256) void score_kernel(const int* __restrict__ batch,
                                                    const float* __restrict__ nodes,
                                                    const float* __restrict__ rel,
                                                    float* __restrict__ out) {
    int wave = (blockIdx.x * blockDim.x + threadIdx.x) >> 6;
    int lane = threadIdx.x & 63;
    if (wave >= NB) return;
    int si = batch[3 * wave], pi = batch[3 * wave + 1], oi = batch[3 * wave + 2];
    float a = nodes[(size_t)si * HID + lane];
    float b = nodes[(size_t)oi * HID + lane];
    float v = a * rel[pi * HID + lane] * b;
#pragma unroll
    for (int off = 32; off; off >>= 1) v += __shfl_down(v, off, 64);
    if (lane == 0) out[wave] = v;
}

extern "C" void kernel_launch(void* const* d_in, const int* in_sizes, int n_in,
                              void* d_out, int out_size, void* d_ws, size_t ws_size,
                              hipStream_t stream) {
    const int*   batch   = (const int*)d_in[0];
    const int*   triples = (const int*)d_in[1];
    const float* w0      = (const float*)d_in[2];
    const float* b0      = (const float*)d_in[3];
    const float* w1      = (const float*)d_in[4];
    const float* b1      = (const float*)d_in[5];
    const float* rel     = (const float*)d_in[6];
    float* out = (float*)d_out;

    // ---- workspace layout: [zeroed: celloff | flag | coloff] | rest ----------
    int* celloff  = (int*)d_ws;                         // M+1
    int* flag     = celloff + (M_CELLS + 1);            // NN
    int* coloff   = flag + NN;                          // M+1 (colflag -> offsets)
    float* vals   = (float*)(coloff + (M_CELLS + 1));   // M
    int* rank     = (int*)(vals + M_CELLS);             // 2NE
    int* pay      = rank + 2 * NE;                      // 2NE + NN
    int* sums     = pay + (2 * NE + NN);                // SCAN_B (shared by both scans)
    int* collist  = sums + SCAN_B;                      // <= M
    float* h      = (float*)(collist + M_CELLS);        // NN*HID
    float* nodes  = h + (size_t)NN * HID;               // NN*HID
    float* g      = nodes + (size_t)NN * HID;           // <= M*HID (expected ~410k rows)

    size_t zero_bytes = ((size_t)2 * (M_CELLS + 1) + NN) * 4;   // ~8.6 MB
    hipMemsetAsync(d_ws, 0, zero_bytes, stream);

    const int htot = NE + NN + 2 * NB;
    hist_kernel<<<(htot + 255) / 256, 256, 0, stream>>>(triples, batch, celloff, rank, flag);
    recip_kernel<<<(M_CELLS + 255) / 256, 256, 0, stream>>>(celloff, vals);

    const int nb = (M_CELLS + 2 * SCAN_B - 1) / (2 * SCAN_B);   // 513
    {   // exclusive scan of celloff counts, total -> celloff[M]
        scan1_kernel<<<nb, SCAN_B, 0, stream>>>(celloff, sums, M_CELLS);
        scan2_kernel<<<1, SCAN_B, 0, stream>>>(sums, nb, celloff + M_CELLS);
        scan3_kernel<<<nb, SCAN_B, 0, stream>>>(celloff, sums, M_CELLS);
    }

    scatter_kernel<<<(NE + NN + 255) / 256, 256, 0, stream>>>(triples, celloff, rank, flag,
                                                              pay, coloff);

    {   // exclusive scan of colflag -> g-row offsets, total (ncols) -> coloff[M]
        scan1_kernel<<<nb, SCAN_B, 0, stream>>>(coloff, sums, M_CELLS);
        scan2_kernel<<<1, SCAN_B, 0, stream>>>(sums, nb, coloff + M_CELLS);
        scan3_kernel<<<nb, SCAN_B, 0, stream>>>(coloff, sums, M_CELLS);
    }
    collist_kernel<<<(M_CELLS + 255) / 256, 256, 0, stream>>>(coloff, collist);

    layer1_kernel<<<(NN * 64 + 255) / 256, 256, 0, stream>>>(celloff, pay, vals, w0, b0, h);

    gcompute_kernel<<<(M_CELLS + 31) / 32, 256, 0, stream>>>(collist, coloff + M_CELLS,
                                                             h, w1, g);

    layer2_kernel<<<(NN * 64 + 255) / 256, 256, 0, stream>>>(celloff, pay, vals, coloff,
                                                             g, b1, flag, nodes);

    score_kernel<<<(NB * 64 + 255) / 256, 256, 0, stream>>>(batch, nodes, rel, out);
}

// Round 2
// 612.522 us; speedup vs baseline: 1.0722x; 1.0234x over previous
//
#include <hip/hip_runtime.h>

#define NN 50000      // nodes
#define NR 10         // relations (one direction)
#define R2 21         // 2*NR+1
#define NE 500000     // triples
#define NB 16384      // batch
#define HID 64
#define SCAN_B 1024
#define M_CELLS (R2 * NN)   // 1,050,000 cells (ss-major: col = ss*NN + src)
#define COL_MASK 0x1FFFFF   // col fits in 21 bits (max 1,049,999)
#define GC_COLS 64

// ---- hist: celloff cell counts (dst*21+ss) w/ rank capture; batch flags ------
// 4 triples/thread via 3x int4 loads (stride 48 B, 16-aligned).
__global__ void hist_kernel(const int* __restrict__ triples, const int* __restrict__ batch,
                            int* __restrict__ celloff, int* __restrict__ rank,
                            int* __restrict__ flag) {
    int t = blockIdx.x * blockDim.x + threadIdx.x;
    if (t < NE / 4) {
        const int4* tp = (const int4*)(triples + 12 * (size_t)t);
        int4 a = tp[0], b = tp[1], c = tp[2];
        int s[4] = {a.x, a.w, b.z, c.y};
        int p[4] = {a.y, b.x, b.w, c.z};
        int o[4] = {a.z, b.y, c.x, c.w};
#pragma unroll
        for (int i = 0; i < 4; ++i) {
            int e = 4 * t + i;
            rank[e]      = atomicAdd(celloff + s[i] * R2 + p[i], 1);        // fwd
            rank[e + NE] = atomicAdd(celloff + o[i] * R2 + (p[i] + NR), 1); // bwd
        }
    } else if (t < NE / 4 + NN) {
        int v = t - NE / 4;
        celloff[v * R2 + 2 * NR] = 1;   // self-loop cell: always exactly 1
    } else if (t < NE / 4 + NN + 2 * NB) {
        int j = t - (NE / 4 + NN);
        int node = (j < NB) ? batch[3 * j] : batch[3 * (j - NB) + 2];
        flag[node] = 1;                 // idempotent
    }
}

// ---- cnt8[ss*NN+x] = column count via the celloff-count permutation (pre-scan)
__global__ void cnt_kernel(const int* __restrict__ celloff, unsigned char* __restrict__ cnt8) {
    int i = blockIdx.x * blockDim.x + threadIdx.x;
    if (i >= M_CELLS) return;
    unsigned ss = (unsigned)i / NN;
    int x = i - ss * NN;
    int c;
    if (ss < NR)          c = celloff[x * R2 + ss + NR];   // #(p=ss, o=x)
    else if (ss < 2 * NR) c = celloff[x * R2 + ss - NR];   // #(p=ss-NR, s=x)
    else                  c = 1;                           // self-loop
    cnt8[i] = (unsigned char)min(c, 255);                  // counts are tiny (<~16)
}

// ---- 2-level exclusive scan, 2 items per thread ------------------------------
__global__ void scan1_kernel(int* __restrict__ data, int* __restrict__ bsums, int M) {
    __shared__ int sm[SCAN_B];
    int i0 = (blockIdx.x * SCAN_B + threadIdx.x) * 2;
    int x0 = (i0     < M) ? data[i0]     : 0;
    int x1 = (i0 + 1 < M) ? data[i0 + 1] : 0;
    int s = x0 + x1;
    sm[threadIdx.x] = s; __syncthreads();
    for (int off = 1; off < SCAN_B; off <<= 1) {
        int v = (threadIdx.x >= off) ? sm[threadIdx.x - off] : 0;
        __syncthreads();
        sm[threadIdx.x] += v;
        __syncthreads();
    }
    int excl = sm[threadIdx.x] - s;
    if (i0     < M) data[i0]     = excl;
    if (i0 + 1 < M) data[i0 + 1] = excl + x0;
    if (threadIdx.x == SCAN_B - 1) bsums[blockIdx.x] = sm[SCAN_B - 1];
}
__global__ void scan2_kernel(int* __restrict__ bsums, int nb, int* __restrict__ total_out) {
    __shared__ int sm[SCAN_B];
    int x = (threadIdx.x < nb) ? bsums[threadIdx.x] : 0;
    sm[threadIdx.x] = x; __syncthreads();
    for (int off = 1; off < SCAN_B; off <<= 1) {
        int v = (threadIdx.x >= off) ? sm[threadIdx.x - off] : 0;
        __syncthreads();
        sm[threadIdx.x] += v;
        __syncthreads();
    }
    if (threadIdx.x < nb) bsums[threadIdx.x] = sm[threadIdx.x] - x;
    if (threadIdx.x == SCAN_B - 1) *total_out = sm[SCAN_B - 1];
}
__global__ void scan3_kernel(int* __restrict__ data, const int* __restrict__ bsums, int M) {
    int i0 = (blockIdx.x * SCAN_B + threadIdx.x) * 2;
    int b = bsums[blockIdx.x];
    if (i0     < M) data[i0]     += b;
    if (i0 + 1 < M) data[i0 + 1] += b;
}

// ---- scatter (atomic-free via rank) + mark needed cols -----------------------
// pay = col | (cnt<<21): count packed so layer1/2 never gather vals.
__global__ void scatter_kernel(const int* __restrict__ triples,
                               const int* __restrict__ celloff,
                               const int* __restrict__ rank,
                               const int* __restrict__ flag,
                               const unsigned char* __restrict__ cnt8,
                               int* __restrict__ pay,
                               int* __restrict__ colflag) {
    int t = blockIdx.x * blockDim.x + threadIdx.x;
    if (t < NE / 4) {
        const int4* tp = (const int4*)(triples + 12 * (size_t)t);
        int4 a = tp[0], b = tp[1], c = tp[2];
        int s[4] = {a.x, a.w, b.z, c.y};
        int p[4] = {a.y, b.x, b.w, c.z};
        int o[4] = {a.z, b.y, c.x, c.w};
        int4 rka = ((const int4*)rank)[t];
        int4 rkb = ((const int4*)(rank + NE))[t];
        int ra[4] = {rka.x, rka.y, rka.z, rka.w};
        int rb[4] = {rkb.x, rkb.y, rkb.z, rkb.w};
#pragma unroll
        for (int i = 0; i < 4; ++i) {
            int col1 = p[i] * NN + o[i];
            int pos1 = celloff[s[i] * R2 + p[i]] + ra[i];
            pay[pos1] = col1 | ((int)cnt8[col1] << 21);
            int col2 = (p[i] + NR) * NN + s[i];
            int pos2 = celloff[o[i] * R2 + (p[i] + NR)] + rb[i];
            pay[pos2] = col2 | ((int)cnt8[col2] << 21);
            if (flag[s[i]]) colflag[col1] = 1;
            if (flag[o[i]]) colflag[col2] = 1;
        }
    } else if (t < NE / 4 + NN) {
        int v = t - NE / 4;
        int pos = celloff[v * R2 + 2 * NR];
        int col = 2 * NR * NN + v;
        pay[pos] = col | (1 << 21);
        if (flag[v]) colflag[col] = 1;
    }
}

// ---- layer 1: wave per dst; packed-cnt LUT; ILP-8 w0 row loads ---------------
// Also folds collist emit (coloff -> collist) since layer1 runs after the scan.
__global__ __launch_bounds__(256) void layer1_kernel(const int* __restrict__ celloff,
                                                     const int* __restrict__ pay,
                                                     const float* __restrict__ w0,
                                                     const float* __restrict__ b0,
                                                     const int* __restrict__ coloff,
                                                     int* __restrict__ collist,
                                                     float* __restrict__ h) {
    __shared__ float lut[256];
    lut[threadIdx.x] = threadIdx.x ? 1.0f / (float)threadIdx.x : 0.f;   // lut[0]=0 -> free padding
    int t = blockIdx.x * blockDim.x + threadIdx.x;
    if (t < M_CELLS) {                        // collist fold (grid covers 3.2M threads)
        int a = coloff[t], b2 = coloff[t + 1];
        if (b2 > a) collist[a] = t;
    }
    __syncthreads();
    int wv = t >> 6;
    int lane = threadIdx.x & 63;
    if (wv >= NN) return;
    int dst = __builtin_amdgcn_readfirstlane(wv);
    int beg = celloff[dst * R2];
    int end = celloff[(dst + 1) * R2];
    float acc = b0[lane];
    for (int base = beg; base < end; base += 64) {
        int idx = base + lane;
        int colv = (idx < end) ? pay[idx] : 0;          // cnt=0 -> v=0
        int m = __builtin_amdgcn_readfirstlane(min(64, end - base));
        int e = 0;
        for (; e + 8 <= m; e += 8) {
            int c0p = __shfl(colv, e,     64);
            int c1p = __shfl(colv, e + 1, 64);
            int c2p = __shfl(colv, e + 2, 64);
            int c3p = __shfl(colv, e + 3, 64);
            int c4p = __shfl(colv, e + 4, 64);
            int c5p = __shfl(colv, e + 5, 64);
            int c6p = __shfl(colv, e + 6, 64);
            int c7p = __shfl(colv, e + 7, 64);
            float f0 = w0[(size_t)(c0p & COL_MASK) * HID + lane];
            float f1 = w0[(size_t)(c1p & COL_MASK) * HID + lane];
            float f2 = w0[(size_t)(c2p & COL_MASK) * HID + lane];
            float f3 = w0[(size_t)(c3p & COL_MASK) * HID + lane];
            float f4 = w0[(size_t)(c4p & COL_MASK) * HID + lane];
            float f5 = w0[(size_t)(c5p & COL_MASK) * HID + lane];
            float f6 = w0[(size_t)(c6p & COL_MASK) * HID + lane];
            float f7 = w0[(size_t)(c7p & COL_MASK) * HID + lane];
            acc += lut[(unsigned)c0p >> 21] * f0;
            acc += lut[(unsigned)c1p >> 21] * f1;
            acc += lut[(unsigned)c2p >> 21] * f2;
            acc += lut[(unsigned)c3p >> 21] * f3;
            acc += lut[(unsigned)c4p >> 21] * f4;
            acc += lut[(unsigned)c5p >> 21] * f5;
            acc += lut[(unsigned)c6p >> 21] * f6;
            acc += lut[(unsigned)c7p >> 21] * f7;
        }
        for (; e < m; ++e) {
            int cp = __shfl(colv, e, 64);
            acc += lut[(unsigned)cp >> 21] * w0[(size_t)(cp & COL_MASK) * HID + lane];
        }
    }
    h[(size_t)dst * HID + lane] = acc;
}

// ---- gcompute: g[gi] = h[src] @ w1[ss] for each flagged col ------------------
// 64 cols/block (halves w1 staging traffic); collist ss-major -> uniform blocks.
__global__ __launch_bounds__(256) void gcompute_kernel(const int* __restrict__ collist,
                                                       const int* __restrict__ ncols_p,
                                                       const float* __restrict__ h,
                                                       const float* __restrict__ w1,
                                                       float* __restrict__ g) {
    __shared__ float w1s[HID * HID];     // 16 KB
    __shared__ float hs[GC_COLS * 68];   // 17.4 KB, pad stride 68
    const int ncols = *ncols_p;
    const int base = blockIdx.x * GC_COLS;
    if (base >= ncols) return;           // uniform early-exit
    const int lane = threadIdx.x & 63;
    const int wid  = __builtin_amdgcn_readfirstlane(threadIdx.x >> 6);
    const int trow = threadIdx.x >> 2;   // 0..63 (staging row)
    const int tc4  = threadIdx.x & 3;    // 0..3  (staging chunk)

    int lastr = min(base + GC_COLS - 1, ncols - 1);
    int col0 = collist[base];
    int colL = collist[lastr];
    int ss0 = (int)((unsigned)col0 / NN);
    int ssL = (int)((unsigned)colL / NN);
    bool uni = (ss0 == ssL);

    {   // stage w1[ss0] (4096 floats = 1024 float4, 256 threads x 4)
        const float4* src = (const float4*)(w1 + (size_t)ss0 * HID * HID);
        float4* dst = (float4*)w1s;
#pragma unroll
        for (int i = 0; i < 4; ++i) dst[threadIdx.x + 256 * i] = src[threadIdx.x + 256 * i];
    }
    {   // stage h rows for this block's cols (64 rows x 16 float4)
        int myrow = base + trow;
        int mycol = (myrow < ncols) ? collist[myrow] : col0;
        int myss  = (int)((unsigned)mycol / NN);
        int mysrc = mycol - myss * NN;
#pragma unroll
        for (int it = 0; it < 4; ++it) {
            int c = tc4 + 4 * it;        // float4 index 0..15
            float4 v = *(const float4*)(h + (size_t)mysrc * HID + c * 4);
            *(float4*)(hs + trow * 68 + c * 4) = v;
        }
    }
    __syncthreads();

    float acc[16];
#pragma unroll
    for (int i = 0; i < 16; ++i) acc[i] = 0.f;

    if (uni) {
#pragma unroll
        for (int kc = 0; kc < 4; ++kc) {
            float wk[16];
#pragma unroll
            for (int k = 0; k < 16; ++k) wk[k] = w1s[(kc * 16 + k) * HID + lane];
#pragma unroll
            for (int ii = 0; ii < 16; ++ii) {
                const float* lp = hs + (wid * 16 + ii) * 68 + kc * 16;
                float4 a0 = *(const float4*)(lp);
                float4 a1 = *(const float4*)(lp + 4);
                float4 a2 = *(const float4*)(lp + 8);
                float4 a3 = *(const float4*)(lp + 12);
                float a = acc[ii];
                a += a0.x * wk[0];  a += a0.y * wk[1];  a += a0.z * wk[2];  a += a0.w * wk[3];
                a += a1.x * wk[4];  a += a1.y * wk[5];  a += a1.z * wk[6];  a += a1.w * wk[7];
                a += a2.x * wk[8];  a += a2.y * wk[9];  a += a2.z * wk[10]; a += a2.w * wk[11];
                a += a3.x * wk[12]; a += a3.y * wk[13]; a += a3.z * wk[14]; a += a3.w * wk[15];
                acc[ii] = a;
            }
        }
    } else {
        // rare ss-boundary block (~20 of ~7k): per-row w1 from global (L2-hot)
        for (int ii = 0; ii < 16; ++ii) {
            int r = base + wid * 16 + ii;
            if (r >= ncols) continue;
            int c = collist[r];
            int ss = (int)((unsigned)c / NN);
            const float* wp = w1 + (size_t)ss * HID * HID;
            const float* lp = hs + (wid * 16 + ii) * 68;
            float a = 0.f;
            for (int k = 0; k < HID; ++k) a += lp[k] * wp[k * HID + lane];
            acc[ii] = a;
        }
    }

#pragma unroll
    for (int ii = 0; ii < 16; ++ii) {
        int r = base + wid * 16 + ii;
        if (r < ncols) g[(size_t)r * HID + lane] = acc[ii];
    }
}

// ---- layer 2: wave per flagged dst; packed-cnt LUT; ILP-8 g-row gather -------
__global__ __launch_bounds__(256) void layer2_kernel(const int* __restrict__ celloff,
                                                     const int* __restrict__ pay,
                                                     const int* __restrict__ coloff,
                                                     const float* __restrict__ g,
                                                     const float* __restrict__ b1,
                                                     const int* __restrict__ flag,
                                                     float* __restrict__ nodes) {
    __shared__ float lut[256];
    lut[threadIdx.x] = threadIdx.x ? 1.0f / (float)threadIdx.x : 0.f;
    __syncthreads();
    int wv = (blockIdx.x * blockDim.x + threadIdx.x) >> 6;
    int lane = threadIdx.x & 63;
    if (wv >= NN) return;
    int dst = __builtin_amdgcn_readfirstlane(wv);
    if (!flag[dst]) return;
    int beg = celloff[dst * R2];
    int end = celloff[(dst + 1) * R2];      // includes self-loop cell (cnt=1)
    float acc = b1[lane];
    for (int base = beg; base < end; base += 64) {
        int idx = base + lane;
        int colv = (idx < end) ? pay[idx] : 0;               // cnt=0 -> v=0
        int gv   = (idx < end) ? coloff[colv & COL_MASK] : 0;
        int m = __builtin_amdgcn_readfirstlane(min(64, end - base));
        int e = 0;
        for (; e + 8 <= m; e += 8) {
            int g0 = __shfl(gv, e,     64); int c0p = __shfl(colv, e,     64);
            int g1 = __shfl(gv, e + 1, 64); int c1p = __shfl(colv, e + 1, 64);
            int g2 = __shfl(gv, e + 2, 64); int c2p = __shfl(colv, e + 2, 64);
            int g3 = __shfl(gv, e + 3, 64); int c3p = __shfl(colv, e + 3, 64);
            int g4 = __shfl(gv, e + 4, 64); int c4p = __shfl(colv, e + 4, 64);
            int g5 = __shfl(gv, e + 5, 64); int c5p = __shfl(colv, e + 5, 64);
            int g6 = __shfl(gv, e + 6, 64); int c6p = __shfl(colv, e + 6, 64);
            int g7 = __shfl(gv, e + 7, 64); int c7p = __shfl(colv, e + 7, 64);
            float f0 = g[(size_t)g0 * HID + lane];
            float f1 = g[(size_t)g1 * HID + lane];
            float f2 = g[(size_t)g2 * HID + lane];
            float f3 = g[(size_t)g3 * HID + lane];
            float f4 = g[(size_t)g4 * HID + lane];
            float f5 = g[(size_t)g5 * HID + lane];
            float f6 = g[(size_t)g6 * HID + lane];
            float f7 = g[(size_t)g7 * HID + lane];
            acc += lut[(unsigned)c0p >> 21] * f0;
            acc += lut[(unsigned)c1p >> 21] * f1;
            acc += lut[(unsigned)c2p >> 21] * f2;
            acc += lut[(unsigned)c3p >> 21] * f3;
            acc += lut[(unsigned)c4p >> 21] * f4;
            acc += lut[(unsigned)c5p >> 21] * f5;
            acc += lut[(unsigned)c6p >> 21] * f6;
            acc += lut[(unsigned)c7p >> 21] * f7;
        }
        for (; e < m; ++e) {
            int gi = __shfl(gv, e, 64);
            int cp = __shfl(colv, e, 64);
            acc += lut[(unsigned)cp >> 21] * g[(size_t)gi * HID + lane];
        }
    }
    nodes[(size_t)dst * HID + lane] = acc;
}

// ---- scores: wave per batch item (nodes indexed directly) --------------------
__global__ __launch_bounds__(256) void score_kernel(const int* __restrict__ batch,
                                                    const float* __restrict__ nodes,
                                                    const float* __restrict__ rel,
                                                    float* __restrict__ out) {
    int wave = (blockIdx.x * blockDim.x + threadIdx.x) >> 6;
    int lane = threadIdx.x & 63;
    if (wave >= NB) return;
    int si = batch[3 * wave], pi = batch[3 * wave + 1], oi = batch[3 * wave + 2];
    float a = nodes[(size_t)si * HID + lane];
    float b = nodes[(size_t)oi * HID + lane];
    float v = a * rel[pi * HID + lane] * b;
#pragma unroll
    for (int off = 32; off; off >>= 1) v += __shfl_down(v, off, 64);
    if (lane == 0) out[wave] = v;
}

extern "C" void kernel_launch(void* const* d_in, const int* in_sizes, int n_in,
                              void* d_out, int out_size, void* d_ws, size_t ws_size,
                              hipStream_t stream) {
    const int*   batch   = (const int*)d_in[0];
    const int*   triples = (const int*)d_in[1];
    const float* w0      = (const float*)d_in[2];
    const float* b0      = (const float*)d_in[3];
    const float* w1      = (const float*)d_in[4];
    const float* b1      = (const float*)d_in[5];
    const float* rel     = (const float*)d_in[6];
    float* out = (float*)d_out;

    // ---- workspace layout: [zeroed: celloff | flag | coloff] | rest ----------
    int* celloff  = (int*)d_ws;                         // M+1
    int* flag     = celloff + (M_CELLS + 1);            // NN
    int* coloff   = flag + NN;                          // M+1 (colflag -> offsets)
    unsigned char* cnt8 = (unsigned char*)(coloff + (M_CELLS + 1));  // M bytes
    int* rank     = (int*)(cnt8 + ((M_CELLS + 15) & ~15));           // 2NE
    int* pay      = rank + 2 * NE;                      // 2NE + NN
    int* sums     = pay + (2 * NE + NN);                // SCAN_B (shared by both scans)
    int* collist  = sums + SCAN_B;                      // <= M
    float* h      = (float*)(collist + M_CELLS);        // NN*HID
    float* nodes  = h + (size_t)NN * HID;               // NN*HID
    float* g      = nodes + (size_t)NN * HID;           // <= M*HID (~450k rows used)

    size_t zero_bytes = ((size_t)2 * (M_CELLS + 1) + NN) * 4;   // ~8.6 MB
    hipMemsetAsync(d_ws, 0, zero_bytes, stream);

    const int htot = NE / 4 + NN + 2 * NB;
    hist_kernel<<<(htot + 255) / 256, 256, 0, stream>>>(triples, batch, celloff, rank, flag);
    cnt_kernel<<<(M_CELLS + 255) / 256, 256, 0, stream>>>(celloff, cnt8);

    const int nb = (M_CELLS + 2 * SCAN_B - 1) / (2 * SCAN_B);   // 513
    {   // exclusive scan of celloff counts, total -> celloff[M]
        scan1_kernel<<<nb, SCAN_B, 0, stream>>>(celloff, sums, M_CELLS);
        scan2_kernel<<<1, SCAN_B, 0, stream>>>(sums, nb, celloff + M_CELLS);
        scan3_kernel<<<nb, SCAN_B, 0, stream>>>(celloff, sums, M_CELLS);
    }

    const int stot = NE / 4 + NN;
    scatter_kernel<<<(stot + 255) / 256, 256, 0, stream>>>(triples, celloff, rank, flag,
                                                           cnt8, pay, coloff);

    {   // exclusive scan of colflag -> g-row offsets, total (ncols) -> coloff[M]
        scan1_kernel<<<nb, SCAN_B, 0, stream>>>(coloff, sums, M_CELLS);
        scan2_kernel<<<1, SCAN_B, 0, stream>>>(sums, nb, coloff + M_CELLS);
        scan3_kernel<<<nb, SCAN_B, 0, stream>>>(coloff, sums, M_CELLS);
    }

    layer1_kernel<<<(NN * 64 + 255) / 256, 256, 0, stream>>>(celloff, pay, w0, b0,
                                                             coloff, collist, h);

    gcompute_kernel<<<(M_CELLS + GC_COLS - 1) / GC_COLS, 256, 0, stream>>>(collist,
                                                             coloff + M_CELLS, h, w1, g);

    layer2_kernel<<<(NN * 64 + 255) / 256, 256, 0, stream>>>(celloff, pay, coloff,
                                                             g, b1, flag, nodes);

    score_kernel<<<(NB * 64 + 255) / 256, 256, 0, stream>>>(batch, nodes, rel, out);
}